// Round 10
// baseline (336.984 us; speedup 1.0000x reference)
//
#include <hip/hip_runtime.h>
#include <hip/hip_bf16.h>
#include <math.h>

// Problem constants: x[B=16][T=4096][D=512], W[512][512], v[512]
#define BB 16
#define TT 4096
#define DD 512
#define MM (BB*TT)   // 65536 rows

typedef __bf16 bf16x8 __attribute__((ext_vector_type(8)));
typedef float  f32x4  __attribute__((ext_vector_type(4)));
typedef float  f32x16 __attribute__((ext_vector_type(16)));

__device__ inline unsigned short f2bf(float f) {
    unsigned u = __builtin_bit_cast(unsigned, f) + 0x8000u;  // round-half-away
    return (unsigned short)(u >> 16);
}

// pack two fp32 -> two bf16 in one u32 (2 v_add + 1 v_perm)
__device__ inline unsigned pack_bf16x2(float lo, float hi) {
    unsigned u0 = __builtin_bit_cast(unsigned, lo) + 0x8000u;
    unsigned u1 = __builtin_bit_cast(unsigned, hi) + 0x8000u;
    return __builtin_amdgcn_perm(u1, u0, 0x07060302);  // [u1.hi16, u0.hi16]
}

// fast tanh: 1 - 2/(e^{2y}+1).  |y| <~ 2 here, no overflow concerns.
__device__ inline float tanh_fast(float y) {
    float e = __expf(2.0f * y);
    return 1.0f - 2.0f * __builtin_amdgcn_rcpf(e + 1.0f);
}

// ---------------- W fp32 -> Wb bf16, 32x32x16 wave-stream fragment order ----------------
// frag id fid = ((qh*4 + p)*32 + s)   (qh = col-quarter, p = 32-col pass, s = K16 step)
// lane of frag holds B[k = s*16 + (lane>>5)*8 + j][n = qh*128 + p*32 + (lane&31)]
// (standard 32x32x16 B layout: k-group = lane>>5, col = lane&31, 8 consecutive k/lane)
// => per col-quarter the K-loop B reads are ONE monotone 1 KB/step 128 KB stream.
__global__ void wb_kernel(const float* __restrict__ W, unsigned short* __restrict__ Wb) {
    int u = blockIdx.x * 256 + threadIdx.x;   // 0..32767
    int lane = u & 63;
    int fid  = u >> 6;                        // 0..511
    int s  = fid & 31;
    int p  = (fid >> 5) & 3;
    int qh = fid >> 7;
    int n  = qh * 128 + p * 32 + (lane & 31);
    int k0 = s * 16 + (lane >> 5) * 8;
    unsigned short o[8];
    #pragma unroll
    for (int j = 0; j < 8; j++) o[j] = f2bf(W[(size_t)(k0 + j) * DD + n]);
    *(uint4*)(Wb + (size_t)u * 8) = *(uint4*)o;   // coalesced 16 B store
}

// ---------------- Fused GEMM + tanh + v-dot + online-softmax partial pool ----------------
// RESOURCE LAW (R5-R9): Sum(waves x VGPR-quantum) <= 1024/CU, quantum in {64,128,256};
// launch_bounds 2nd arg caps VGPR at 256/arg.  The 16x16x32 shape cannot fit a useful
// K-loop in 64 regs (R5/R7 spill) and caps at 8 waves/CU in the 128 slot (R3/R8).
// FIX: mfma_f32_32x32x16_bf16.  A-frag = 32 rows x K16 in 4 regs, B-frag 4 regs,
// acc 16 regs for a 32x32 tile.  K-loop steady state: acc 16 + b-ring4 16 + a-ring2 8
// + addr ~15 ~= 55-60 -> fits the 64-VGPR quantum -> 16 waves/CU (2x TLP), AND each
// K16 step is 1 ds_read + 1 b-load + 1 MFMA (half the non-MFMA instrs of 16x16x32).
// Block = 32 rows, 256 thr (4 waves); wave w = 32 rows x col-quarter w, 4 passes of
// a 32x32 acc tile (full-K accumulate).  LDS ~37 KB -> 4 blocks/CU (R7-proven).
// A-strip (32x512 bf16 = 32 KB) staged ONCE via NT loads (keep W L2-resident).
// ZERO barriers in the K-loop.  Tripwire: WRITE_SIZE >> 4 MB => spilled.
__global__ __launch_bounds__(256, 4) void scorepool_kernel(
        const float* __restrict__ x, const unsigned short* __restrict__ Wb,
        const float* __restrict__ v,
        float* __restrict__ num_ws, float* __restrict__ mz_ws) {
    __shared__ unsigned short As[32 * DD];   // 32 KB
    __shared__ float sbuf[4][32];
    __shared__ float ew[32];
    __shared__ float mzsh[2];
    __shared__ float psum[2][DD];            // 4 KB

    const int tid  = threadIdx.x;
    const int m0   = blockIdx.x * 32;
    const int lane = tid & 63;
    const int wh   = tid >> 6;         // wave col quarter (0..3)
    const int R    = lane & 31;        // A row / B col within the 32-tile
    const int hi   = lane >> 5;        // K half-group
    const int r7   = R & 7;

    // zero the per-wave score accumulators (written by pass epilogues)
    if (tid < 128) ((float*)sbuf)[tid] = 0.f;

    // ---- Stage A: 32 rows x 512 cols fp32 -> bf16, XOR-swizzled.  NT loads:
    //      x is single-use here; keep it out of L2's LRU so W stays resident.
    #pragma unroll 4
    for (int i = 0; i < 8; i++) {
        int u = i * 256 + tid;           // 0..2047 (16-B output chunk id)
        int r = u >> 6;                  // 64 chunks per row, rows 0..31
        int c = u & 63;
        const float* gp = x + (size_t)(m0 + r) * DD + c * 8;
        f32x4 f0 = __builtin_nontemporal_load((const f32x4*)(gp));
        f32x4 f1 = __builtin_nontemporal_load((const f32x4*)(gp + 4));
        uint4 o;
        o.x = pack_bf16x2(f0.x, f0.y);
        o.y = pack_bf16x2(f0.z, f0.w);
        o.z = pack_bf16x2(f1.x, f1.y);
        o.w = pack_bf16x2(f1.z, f1.w);
        *(uint4*)(&As[r * DD + (c ^ (r & 7)) * 8]) = o;
    }

    // ---- Prime B ring (quarter stream: contiguous 128 KB at wh*65536 shorts).
    const unsigned short* bqp = Wb + (size_t)wh * 65536 + lane * 8;
    bf16x8 b[4];
    #pragma unroll
    for (int g = 0; g < 3; g++) {
        b[g] = *(const bf16x8*)(bqp);
        bqp += 512;                      // one 1 KB frag per K16 step
    }

    __syncthreads();   // the only barrier before the epilogue

    // A-frag (32x32x16): lane holds A[row=R][k = s*16 + hi*8 + j].
    // 16-B chunk index c = s*2 + hi, stored at c^(R&7) by the staging swizzle.
#define A_FRAG(s) (*(const bf16x8*)(&As[R * DD + ((((s) * 2 + hi) ^ r7) * 8)]))

    bf16x8 a[2];                       // ring-2 over s, 1-step lookahead
    a[0] = A_FRAG(0);

    #pragma unroll 1
    for (int p = 0; p < 4; p++) {      // 4 passes of 32 cols = this wave's quarter
        f32x16 acc;
        #pragma unroll
        for (int j = 0; j < 16; j++) acc[j] = 0.f;

        #pragma unroll
        for (int s = 0; s < 32; s++) {
            a[(s + 1) & 1] = A_FRAG((s + 1) & 31);   // pass p+1 reuses same A (wraps)
            // B stream, 3-step lookahead (stream padded: tail overrun harmless)
            b[(s + 3) & 3] = *(const bf16x8*)(bqp);
            bqp += 512;
            acc = __builtin_amdgcn_mfma_f32_32x32x16_bf16(a[s & 1], b[s & 3], acc, 0, 0, 0);
        }

        // per-pass epilogue: tanh + v-dot, reduce over the 32 col-lanes, accumulate
        // into this wave's private LDS score row.
        // C/D layout (32x32): col = lane&31, row = (reg&3)+8*(reg>>2)+4*(lane>>5)
        // [m74/m101 verified]
        float vv = v[wh * 128 + p * 32 + R];
        #pragma unroll
        for (int reg = 0; reg < 16; reg++) {
            float sum = tanh_fast(acc[reg]) * vv;
            sum += __shfl_xor(sum, 1);
            sum += __shfl_xor(sum, 2);
            sum += __shfl_xor(sum, 4);
            sum += __shfl_xor(sum, 8);
            sum += __shfl_xor(sum, 16);
            if (R == 0)
                sbuf[wh][(reg & 3) + 8 * (reg >> 2) + 4 * hi] += sum;
        }
    }
#undef A_FRAG

    __syncthreads();

    // lanes 0..31 of wave 0: row scores (sum of 4 quarter-partials) -> m, e_r, Z
    if (tid < 32) {
        float s = sbuf[0][tid] + sbuf[1][tid] + sbuf[2][tid] + sbuf[3][tid];
        float m = s;
        #pragma unroll
        for (int off = 16; off; off >>= 1) m = fmaxf(m, __shfl_xor(m, off));
        float e = __expf(s - m);
        float z = e;
        #pragma unroll
        for (int off = 16; off; off >>= 1) z += __shfl_xor(z, off);
        ew[tid] = e;
        if (tid == 0) { mzsh[0] = m; mzsh[1] = z; }
    }
    __syncthreads();

    // weighted x-sum from LDS (first 2 waves): thread = (rg row group, cx chunk)
    // num[d] partial = sum_r e_r * xb[r][d]
    const int cx = tid & 63;
    const int rg = tid >> 6;           // 0..1 used
    if (tid < 128) {
        float nacc[8];
        #pragma unroll
        for (int j = 0; j < 8; j++) nacc[j] = 0.f;
        #pragma unroll 4
        for (int i = 0; i < 16; i++) {
            int r = rg * 16 + i;
            uint4 u = *(const uint4*)(&As[r * DD + ((cx ^ (r & 7)) * 8)]);
            float e = ew[r];
            nacc[0] += e * __builtin_bit_cast(float, u.x << 16);
            nacc[1] += e * __builtin_bit_cast(float, u.x & 0xFFFF0000u);
            nacc[2] += e * __builtin_bit_cast(float, u.y << 16);
            nacc[3] += e * __builtin_bit_cast(float, u.y & 0xFFFF0000u);
            nacc[4] += e * __builtin_bit_cast(float, u.z << 16);
            nacc[5] += e * __builtin_bit_cast(float, u.z & 0xFFFF0000u);
            nacc[6] += e * __builtin_bit_cast(float, u.w << 16);
            nacc[7] += e * __builtin_bit_cast(float, u.w & 0xFFFF0000u);
        }
        *(float4*)(&psum[rg][cx * 8])     = *(float4*)(&nacc[0]);
        *(float4*)(&psum[rg][cx * 8 + 4]) = *(float4*)(&nacc[4]);
    }
    __syncthreads();

    if (tid < 128) {
        int c = tid * 4;
        f32x4 f = *(const f32x4*)(&psum[0][c]);
        f += *(const f32x4*)(&psum[1][c]);
        __builtin_nontemporal_store(f, (f32x4*)(num_ws + (size_t)blockIdx.x * DD + c));
    }
    if (tid == 0) {
        mz_ws[2 * blockIdx.x]     = mzsh[0];
        mz_ws[2 * blockIdx.x + 1] = mzsh[1];
    }
}

// ---------------- Combine: merge 128 chunk-partials per batch -> out[b][512] ----------------
__global__ void combine_kernel(const float* __restrict__ num_ws,
                               const float* __restrict__ mz_ws,
                               float* __restrict__ out) {
    __shared__ float red[4];
    __shared__ float red2[4];
    __shared__ float fs[128];
    const int b   = blockIdx.x;
    const int tid = threadIdx.x;

    float m = -1e30f, z = 0.f;
    if (tid < 128) {
        m = mz_ws[(b * 128 + tid) * 2];
        z = mz_ws[(b * 128 + tid) * 2 + 1];
    }
    float M = m;
    #pragma unroll
    for (int off = 32; off; off >>= 1) M = fmaxf(M, __shfl_xor(M, off));
    if ((tid & 63) == 0) red[tid >> 6] = M;
    __syncthreads();
    M = fmaxf(fmaxf(red[0], red[1]), fmaxf(red[2], red[3]));

    float f  = (tid < 128) ? __expf(m - M) : 0.f;
    float fz = f * z;
    #pragma unroll
    for (int off = 32; off; off >>= 1) fz += __shfl_xor(fz, off);
    if ((tid & 63) == 0) red2[tid >> 6] = fz;
    if (tid < 128) fs[tid] = f;
    __syncthreads();
    const float sinv = 1.0f / (red2[0] + red2[1] + red2[2] + red2[3]);

    float a0 = 0.f, a1 = 0.f;
    #pragma unroll 4
    for (int c = 0; c < 128; c++) {
        float fc = fs[c];
        const float* np = num_ws + (size_t)(b * 128 + c) * DD;
        a0 += fc * np[tid];
        a1 += fc * np[tid + 256];
    }
    out[b * DD + tid]       = a0 * sinv;
    out[b * DD + tid + 256] = a1 * sinv;
}

extern "C" void kernel_launch(void* const* d_in, const int* in_sizes, int n_in,
                              void* d_out, int out_size, void* d_ws, size_t ws_size,
                              hipStream_t stream) {
    (void)in_sizes; (void)n_in; (void)out_size; (void)ws_size;
    const float* x = (const float*)d_in[0];
    const float* W = (const float*)d_in[1];
    const float* v = (const float*)d_in[2];
    float* out = (float*)d_out;

    // ws: Wb 512 KB + 16 KB stream-overrun pad | num 2048x512 fp32 (4 MB) | mz 2048x2 fp32
    unsigned short* Wb = (unsigned short*)d_ws;
    float* num_ws      = (float*)((char*)d_ws + 512 * 1024 + 16 * 1024);
    float* mz_ws       = (float*)((char*)d_ws + 512 * 1024 + 16 * 1024 + 4 * 1024 * 1024);

    wb_kernel<<<128, 256, 0, stream>>>(W, Wb);

    scorepool_kernel<<<MM / 32, 256, 0, stream>>>(x, Wb, v, num_ws, mz_ws);

    combine_kernel<<<BB, 256, 0, stream>>>(num_ws, mz_ws, out);
}

// Round 11
// 293.980 us; speedup vs baseline: 1.1463x; 1.1463x over previous
//
#include <hip/hip_runtime.h>
#include <hip/hip_bf16.h>
#include <math.h>

// Problem constants: x[B=16][T=4096][D=512], W[512][512], v[512]
#define BB 16
#define TT 4096
#define DD 512
#define MM (BB*TT)   // 65536 rows

typedef __bf16 bf16x8 __attribute__((ext_vector_type(8)));
typedef float  f32x4  __attribute__((ext_vector_type(4)));
typedef float  f32x16 __attribute__((ext_vector_type(16)));

__device__ inline unsigned short f2bf(float f) {
    unsigned u = __builtin_bit_cast(unsigned, f) + 0x8000u;  // round-half-away
    return (unsigned short)(u >> 16);
}

// pack two fp32 -> two bf16 in one u32 (2 v_add + 1 v_perm)
__device__ inline unsigned pack_bf16x2(float lo, float hi) {
    unsigned u0 = __builtin_bit_cast(unsigned, lo) + 0x8000u;
    unsigned u1 = __builtin_bit_cast(unsigned, hi) + 0x8000u;
    return __builtin_amdgcn_perm(u1, u0, 0x07060302);  // [u1.hi16, u0.hi16]
}

// fast tanh: 1 - 2/(e^{2y}+1).  |y| <~ 2 here, no overflow concerns.
__device__ inline float tanh_fast(float y) {
    float e = __expf(2.0f * y);
    return 1.0f - 2.0f * __builtin_amdgcn_rcpf(e + 1.0f);
}

// ---------------- W fp32 -> Wb bf16, 32x32x16 wave-stream fragment order ----------------
// frag id fid = ((qh*4 + p)*32 + s)   (qh = col-quarter, p = 32-col pass, s = K16 step)
// lane of frag holds B[k = s*16 + (lane>>5)*8 + j][n = qh*128 + p*32 + (lane&31)]
// => per col-quarter the K-loop B reads are ONE monotone 1 KB/step 128 KB stream.
// VERIFIED correct in R10 (passed, absmax 2.4e-4).
__global__ void wb_kernel(const float* __restrict__ W, unsigned short* __restrict__ Wb) {
    int u = blockIdx.x * 256 + threadIdx.x;   // 0..32767
    int lane = u & 63;
    int fid  = u >> 6;                        // 0..511
    int s  = fid & 31;
    int p  = (fid >> 5) & 3;
    int qh = fid >> 7;
    int n  = qh * 128 + p * 32 + (lane & 31);
    int k0 = s * 16 + (lane >> 5) * 8;
    unsigned short o[8];
    #pragma unroll
    for (int j = 0; j < 8; j++) o[j] = f2bf(W[(size_t)(k0 + j) * DD + n]);
    *(uint4*)(Wb + (size_t)u * 8) = *(uint4*)o;   // coalesced 16 B store
}

// ---------------- Fused GEMM + tanh + v-dot + online-softmax partial pool ----------------
// RESOURCE LAW (R5-R10, final): Sum(waves x VGPR-quantum) <= 1024/CU, quantum in
// {64,128,256}; launch_bounds 2nd arg caps VGPR at 256/arg.  The 64-quantum is
// UNREACHABLE: every <=64 attempt spilled (R5/R7/R10) — working-set floor ~85 regs.
// So we take the 128 slot (8 waves/CU) and instead DIVIDE THE PER-WAVE STALL:
// steady-state wall-step ~= L2-latency / lookahead-depth (matches R3: ~190 cyc at
// 3-step).  32x32x16 fragments (4 regs each) make deep rings affordable:
//   acc 16 + b-ring-8 32 + a-ring-4 16 + addr/temps ~25 ~= 90 <= 128 cap.
// 7-step B lookahead -> wall-step ~45-70 cyc (~3x better than R3).  Each K16 step
// is 1 ds_read + 1 b-load + 1 MFMA (half the non-MFMA instrs of 16x16x32).
// Block = 32 rows, 256 thr (4 waves); wave w = 32 rows x col-quarter w, 4 passes
// of a 32x32 acc tile (full-K accumulate).  A-strip (32 KB) staged ONCE via NT
// loads (keep W L2-resident).  ZERO barriers in the K-loop.
// Tripwire: WRITE_SIZE >> 4 MB => spilled => revert.
__global__ __launch_bounds__(256, 2) void scorepool_kernel(
        const float* __restrict__ x, const unsigned short* __restrict__ Wb,
        const float* __restrict__ v,
        float* __restrict__ num_ws, float* __restrict__ mz_ws) {
    __shared__ unsigned short As[32 * DD];   // 32 KB
    __shared__ float sbuf[4][32];
    __shared__ float ew[32];
    __shared__ float mzsh[2];
    __shared__ float psum[2][DD];            // 4 KB

    const int tid  = threadIdx.x;
    const int m0   = blockIdx.x * 32;
    const int lane = tid & 63;
    const int wh   = tid >> 6;         // wave col quarter (0..3)
    const int R    = lane & 31;        // A row / B col within the 32-tile
    const int hi   = lane >> 5;        // K half-group
    const int r7   = R & 7;

    // zero the per-wave score accumulators (written by pass epilogues)
    if (tid < 128) ((float*)sbuf)[tid] = 0.f;

    // ---- Stage A: 32 rows x 512 cols fp32 -> bf16, XOR-swizzled.  NT loads:
    //      x is single-use here; keep it out of L2's LRU so W stays resident.
    #pragma unroll 4
    for (int i = 0; i < 8; i++) {
        int u = i * 256 + tid;           // 0..2047 (16-B output chunk id)
        int r = u >> 6;                  // 64 chunks per row, rows 0..31
        int c = u & 63;
        const float* gp = x + (size_t)(m0 + r) * DD + c * 8;
        f32x4 f0 = __builtin_nontemporal_load((const f32x4*)(gp));
        f32x4 f1 = __builtin_nontemporal_load((const f32x4*)(gp + 4));
        uint4 o;
        o.x = pack_bf16x2(f0.x, f0.y);
        o.y = pack_bf16x2(f0.z, f0.w);
        o.z = pack_bf16x2(f1.x, f1.y);
        o.w = pack_bf16x2(f1.z, f1.w);
        *(uint4*)(&As[r * DD + (c ^ (r & 7)) * 8]) = o;
    }

    // ---- Prime B ring-8 (quarter stream: contiguous 128 KB at wh*65536 shorts).
    //      7-step lookahead; wh=3 tail overrun 7 KB lands in the 16 KB ws pad.
    const unsigned short* bqp = Wb + (size_t)wh * 65536 + lane * 8;
    bf16x8 b[8];
    #pragma unroll
    for (int g = 0; g < 7; g++) {
        b[g] = *(const bf16x8*)(bqp);
        bqp += 512;                      // one 1 KB frag per K16 step
    }

    __syncthreads();   // the only barrier before the epilogue

    // A-frag (32x32x16): lane holds A[row=R][k = s*16 + hi*8 + j].
    // 16-B chunk index c = s*2 + hi, stored at c^(R&7) by the staging swizzle.
#define A_FRAG(s) (*(const bf16x8*)(&As[R * DD + ((((s) * 2 + hi) ^ r7) * 8)]))

    bf16x8 a[4];                       // ring-4 over s, 3-step lookahead
    a[0] = A_FRAG(0);
    a[1] = A_FRAG(1);
    a[2] = A_FRAG(2);

    #pragma unroll 1
    for (int p = 0; p < 4; p++) {      // 4 passes of 32 cols = this wave's quarter
        f32x16 acc;
        #pragma unroll
        for (int j = 0; j < 16; j++) acc[j] = 0.f;

        #pragma unroll
        for (int s = 0; s < 32; s++) {
            a[(s + 3) & 3] = A_FRAG((s + 3) & 31);   // pass p+1 reuses same A (wraps)
            // B stream, 7-step lookahead (stream padded: tail overrun harmless)
            b[(s + 7) & 7] = *(const bf16x8*)(bqp);
            bqp += 512;
            acc = __builtin_amdgcn_mfma_f32_32x32x16_bf16(a[s & 3], b[s & 7], acc, 0, 0, 0);
        }

        // per-pass epilogue: tanh + v-dot, reduce over the 32 col-lanes, accumulate
        // into this wave's private LDS score row.
        // C/D layout (32x32): col = lane&31, row = (reg&3)+8*(reg>>2)+4*(lane>>5)
        // [m74/m101 verified; R10 end-to-end verified]
        float vv = v[wh * 128 + p * 32 + R];
        #pragma unroll
        for (int reg = 0; reg < 16; reg++) {
            float sum = tanh_fast(acc[reg]) * vv;
            sum += __shfl_xor(sum, 1);
            sum += __shfl_xor(sum, 2);
            sum += __shfl_xor(sum, 4);
            sum += __shfl_xor(sum, 8);
            sum += __shfl_xor(sum, 16);
            if (R == 0)
                sbuf[wh][(reg & 3) + 8 * (reg >> 2) + 4 * hi] += sum;
        }
    }
#undef A_FRAG

    __syncthreads();

    // lanes 0..31 of wave 0: row scores (sum of 4 quarter-partials) -> m, e_r, Z
    if (tid < 32) {
        float s = sbuf[0][tid] + sbuf[1][tid] + sbuf[2][tid] + sbuf[3][tid];
        float m = s;
        #pragma unroll
        for (int off = 16; off; off >>= 1) m = fmaxf(m, __shfl_xor(m, off));
        float e = __expf(s - m);
        float z = e;
        #pragma unroll
        for (int off = 16; off; off >>= 1) z += __shfl_xor(z, off);
        ew[tid] = e;
        if (tid == 0) { mzsh[0] = m; mzsh[1] = z; }
    }
    __syncthreads();

    // weighted x-sum from LDS (first 2 waves): thread = (rg row group, cx chunk)
    // num[d] partial = sum_r e_r * xb[r][d]
    const int cx = tid & 63;
    const int rg = tid >> 6;           // 0..1 used
    if (tid < 128) {
        float nacc[8];
        #pragma unroll
        for (int j = 0; j < 8; j++) nacc[j] = 0.f;
        #pragma unroll 4
        for (int i = 0; i < 16; i++) {
            int r = rg * 16 + i;
            uint4 u = *(const uint4*)(&As[r * DD + ((cx ^ (r & 7)) * 8)]);
            float e = ew[r];
            nacc[0] += e * __builtin_bit_cast(float, u.x << 16);
            nacc[1] += e * __builtin_bit_cast(float, u.x & 0xFFFF0000u);
            nacc[2] += e * __builtin_bit_cast(float, u.y << 16);
            nacc[3] += e * __builtin_bit_cast(float, u.y & 0xFFFF0000u);
            nacc[4] += e * __builtin_bit_cast(float, u.z << 16);
            nacc[5] += e * __builtin_bit_cast(float, u.z & 0xFFFF0000u);
            nacc[6] += e * __builtin_bit_cast(float, u.w << 16);
            nacc[7] += e * __builtin_bit_cast(float, u.w & 0xFFFF0000u);
        }
        *(float4*)(&psum[rg][cx * 8])     = *(float4*)(&nacc[0]);
        *(float4*)(&psum[rg][cx * 8 + 4]) = *(float4*)(&nacc[4]);
    }
    __syncthreads();

    if (tid < 128) {
        int c = tid * 4;
        f32x4 f = *(const f32x4*)(&psum[0][c]);
        f += *(const f32x4*)(&psum[1][c]);
        __builtin_nontemporal_store(f, (f32x4*)(num_ws + (size_t)blockIdx.x * DD + c));
    }
    if (tid == 0) {
        mz_ws[2 * blockIdx.x]     = mzsh[0];
        mz_ws[2 * blockIdx.x + 1] = mzsh[1];
    }
}

// ---------------- Combine: merge 128 chunk-partials per batch -> out[b][512] ----------------
__global__ void combine_kernel(const float* __restrict__ num_ws,
                               const float* __restrict__ mz_ws,
                               float* __restrict__ out) {
    __shared__ float red[4];
    __shared__ float red2[4];
    __shared__ float fs[128];
    const int b   = blockIdx.x;
    const int tid = threadIdx.x;

    float m = -1e30f, z = 0.f;
    if (tid < 128) {
        m = mz_ws[(b * 128 + tid) * 2];
        z = mz_ws[(b * 128 + tid) * 2 + 1];
    }
    float M = m;
    #pragma unroll
    for (int off = 32; off; off >>= 1) M = fmaxf(M, __shfl_xor(M, off));
    if ((tid & 63) == 0) red[tid >> 6] = M;
    __syncthreads();
    M = fmaxf(fmaxf(red[0], red[1]), fmaxf(red[2], red[3]));

    float f  = (tid < 128) ? __expf(m - M) : 0.f;
    float fz = f * z;
    #pragma unroll
    for (int off = 32; off; off >>= 1) fz += __shfl_xor(fz, off);
    if ((tid & 63) == 0) red2[tid >> 6] = fz;
    if (tid < 128) fs[tid] = f;
    __syncthreads();
    const float sinv = 1.0f / (red2[0] + red2[1] + red2[2] + red2[3]);

    float a0 = 0.f, a1 = 0.f;
    #pragma unroll 4
    for (int c = 0; c < 128; c++) {
        float fc = fs[c];
        const float* np = num_ws + (size_t)(b * 128 + c) * DD;
        a0 += fc * np[tid];
        a1 += fc * np[tid + 256];
    }
    out[b * DD + tid]       = a0 * sinv;
    out[b * DD + tid + 256] = a1 * sinv;
}

extern "C" void kernel_launch(void* const* d_in, const int* in_sizes, int n_in,
                              void* d_out, int out_size, void* d_ws, size_t ws_size,
                              hipStream_t stream) {
    (void)in_sizes; (void)n_in; (void)out_size; (void)ws_size;
    const float* x = (const float*)d_in[0];
    const float* W = (const float*)d_in[1];
    const float* v = (const float*)d_in[2];
    float* out = (float*)d_out;

    // ws: Wb 512 KB + 16 KB stream-overrun pad | num 2048x512 fp32 (4 MB) | mz 2048x2 fp32
    unsigned short* Wb = (unsigned short*)d_ws;
    float* num_ws      = (float*)((char*)d_ws + 512 * 1024 + 16 * 1024);
    float* mz_ws       = (float*)((char*)d_ws + 512 * 1024 + 16 * 1024 + 4 * 1024 * 1024);

    wb_kernel<<<128, 256, 0, stream>>>(W, Wb);

    scorepool_kernel<<<MM / 32, 256, 0, stream>>>(x, Wb, v, num_ws, mz_ws);

    combine_kernel<<<BB, 256, 0, stream>>>(num_ws, mz_ws, out);
}